// Round 3
// baseline (606.519 us; speedup 1.0000x reference)
//
#include <hip/hip_runtime.h>
#include <cstdint>
#include <cstddef>

// ---------------------------------------------------------------------------
// CausalSelfAttention, B=4 T=2048 C=2048 H=16 D=128, fp32 in/out.
// cvt(fp32->bf16) -> gemm_qkv (256x256 8-phase counted-vmcnt, fused rope,
// LDS-coalesced epilogue, XCD-swizzled grid; Q,K stored D-INTERLEAVED
// d' = 2*(d&63)+(d>>6) -- QK^T invariant under shared d-permutation;
// V^T tiled (B,H,32,128,64)) -> fattn (flash, K/V double-buffered counted
// vmcnt) -> gemm_proj (256x256 8-phase, XCD-swizzled, fp32 out).
// NOTE: no LDS-pointer arrays (hipcc addrspacecast static-init bug) --
// double-buffer selection is arithmetic offset off a single smem base.
// Workspace layout (bytes):
//   0         Wq_b   (6144x2048 bf16)  25165824
//   25165824  Wp_b   (2048x2048 bf16)   8388608
//   33554432  x_b    (8192x2048 bf16)  33554432
//   67108864  Qb     (B,H,T,D' bf16)   33554432   (d-interleaved)
//   100663296 Kb     (B,H,T,D' bf16)   33554432   (d-interleaved)
//   134217728 Vt     tiled (B,H,32,128,64) bf16  33554432
//   167772160 Yb     (8192x2048 bf16)  33554432
// ---------------------------------------------------------------------------

typedef unsigned short u16;
typedef u16    u16x8 __attribute__((ext_vector_type(8)));
typedef __bf16 bf16x8 __attribute__((ext_vector_type(8)));
typedef float  f32x4 __attribute__((ext_vector_type(4)));

#define MFMA16(a, b, c) __builtin_amdgcn_mfma_f32_16x16x32_bf16( \
    __builtin_bit_cast(bf16x8, (a)), __builtin_bit_cast(bf16x8, (b)), (c), 0, 0, 0)

static __device__ __forceinline__ u16 f2b(float f) {
  unsigned u = __builtin_bit_cast(unsigned, f);
  unsigned r = (u + 0x7FFFu + ((u >> 16) & 1u)) >> 16;   // RNE
  return (u16)r;
}

// async global->LDS, 16B per lane; lds dest = (wave-uniform base) + lane*16
static __device__ __forceinline__ void gld_lds16(const void* g, void* l) {
  __builtin_amdgcn_global_load_lds(
      (__attribute__((address_space(1))) unsigned int*)(void*)(g),
      (__attribute__((address_space(3))) unsigned int*)(l),
      16, 0, 0);
}

#define BARRIER() asm volatile("s_barrier" ::: "memory")
#define LGKM0()   do { asm volatile("s_waitcnt lgkmcnt(0)" ::: "memory"); \
                       __builtin_amdgcn_sched_barrier(0); } while (0)
#define WAIT_VM(n) asm volatile("s_waitcnt vmcnt(" #n ")" ::: "memory")

// ---------------------------------------------------------------------------
// fp32 -> bf16 conversion, 8 elements/thread
// ---------------------------------------------------------------------------
__global__ __launch_bounds__(256) void cvt_bf16(const float4* __restrict__ src,
                                                u16x8* __restrict__ dst, int n8) {
  int i = blockIdx.x * 256 + threadIdx.x;
  if (i >= n8) return;
  float4 a = src[i * 2], b = src[i * 2 + 1];
  u16x8 o;
  o[0] = f2b(a.x); o[1] = f2b(a.y); o[2] = f2b(a.z); o[3] = f2b(a.w);
  o[4] = f2b(b.x); o[5] = f2b(b.y); o[6] = f2b(b.z); o[7] = f2b(b.w);
  dst[i] = o;
}

// ---------------------------------------------------------------------------
// 256x256 8-phase GEMM main loop (shared by gemm_qkv / gemm_proj).
// A: MxK row-major bf16, Bw: NxK row-major bf16 (computes A @ Bw^T).
// acc[i][j]: rows wm*128+i*16, cols wn*64+j*16; C/D layout row=quad*4+reg,
// col=lane&15. LDS per buffer: A[256][64] then B[256][64], chunk swizzle.
// ---------------------------------------------------------------------------
static __device__ __forceinline__ void rdA(u16x8 (&af)[4][2], const u16* p,
                                           int cx0, int cx1) {
#pragma unroll
  for (int i = 0; i < 4; ++i) {
    af[i][0] = *(const u16x8*)(p + i * 1024 + cx0);
    af[i][1] = *(const u16x8*)(p + i * 1024 + cx1);
  }
}

static __device__ __forceinline__ void rdB(u16x8 (&bf)[2][2], const u16* p,
                                           int cx0, int cx1) {
#pragma unroll
  for (int j = 0; j < 2; ++j) {
    bf[j][0] = *(const u16x8*)(p + j * 1024 + cx0);
    bf[j][1] = *(const u16x8*)(p + j * 1024 + cx1);
  }
}

static __device__ __forceinline__ void mm16(f32x4 (&acc)[8][4], int ib, int jb,
                                            const u16x8 (&af)[4][2],
                                            const u16x8 (&bf)[2][2]) {
#pragma unroll
  for (int i = 0; i < 4; ++i)
#pragma unroll
    for (int j = 0; j < 2; ++j) {
      acc[ib + i][jb + j] = MFMA16(af[i][0], bf[j][0], acc[ib + i][jb + j]);
      acc[ib + i][jb + j] = MFMA16(af[i][1], bf[j][1], acc[ib + i][jb + j]);
    }
}

static __device__ __forceinline__ void gemm256_main(
    const u16* __restrict__ A, const u16* __restrict__ Bw, int K,
    int m0, int n0, u16* sm, f32x4 (&acc)[8][4]) {
  const int tid = threadIdx.x;
  const int lane = tid & 63, wv = tid >> 6;
  const int quad = lane >> 4, col = lane & 15;
  const int wm = wv >> 2, wn = wv & 3;

  u16* LA0 = sm;                // buf0 A  (32KB = 16384 u16)
  u16* LB0 = sm + 16384;        // buf0 B
  u16* LA1 = sm + 32768;        // buf1 A
  u16* LB1 = sm + 49152;        // buf1 B

#pragma unroll
  for (int i = 0; i < 8; ++i)
#pragma unroll
    for (int j = 0; j < 4; ++j) acc[i][j] = (f32x4){0.f, 0.f, 0.f, 0.f};

  const int r8 = lane >> 3, ch = lane & 7;
  const int sc8 = (ch ^ r8) << 3;           // row&7 == r8 for our row layout
  const u16 *aS[4], *bS[4];
  int dof[4];
#pragma unroll
  for (int u = 0; u < 4; ++u) {
    int row = u * 64 + wv * 8 + r8;
    aS[u] = A + (size_t)(m0 + row) * K + sc8;
    bS[u] = Bw + (size_t)(n0 + row) * K + sc8;
    dof[u] = (u * 64 + wv * 8) * 64;
  }

  const int cx0 = ((quad) ^ (col & 7)) << 3;
  const int cx1 = ((4 | quad) ^ (col & 7)) << 3;
  const int offA = (wm * 128 + col) * 64;
  const int offB = (wn * 64 + col) * 64;

  // ---- prologue: stage tile0 -> buf0, order B0..B3, A0, A2, A1, A3 ----
  gld_lds16(bS[0], LB0 + dof[0]); gld_lds16(bS[1], LB0 + dof[1]);
  gld_lds16(bS[2], LB0 + dof[2]); gld_lds16(bS[3], LB0 + dof[3]);
  gld_lds16(aS[0], LA0 + dof[0]); gld_lds16(aS[2], LA0 + dof[2]);
  gld_lds16(aS[1], LA0 + dof[1]); gld_lds16(aS[3], LA0 + dof[3]);
  WAIT_VM(2);          // first 6 (B0-3, A0, A2) landed; A1,A3 in flight
  BARRIER();

  u16x8 af[4][2], bfL[2][2], bfH[2][2];
  const int nIt = K >> 7;
#pragma unroll 1
  for (int it = 0; it < nIt; ++it) {
    const size_t ko = (size_t)it * 128 + 64;
    const size_t kn = (size_t)it * 128 + 128;
    const bool hn = (it + 1 < nIt);

    // ---------- e.q0 ----------
    rdA(af, LA0 + offA, cx0, cx1);
    rdB(bfL, LB0 + offB, cx0, cx1);
    gld_lds16(bS[0] + ko, LB1 + dof[0]); gld_lds16(bS[1] + ko, LB1 + dof[1]);
    BARRIER(); LGKM0();
    __builtin_amdgcn_s_setprio(1); mm16(acc, 0, 0, af, bfL);
    __builtin_amdgcn_s_setprio(0);
    BARRIER();
    // ---------- e.q1 ----------
    rdB(bfH, LB0 + offB + 2048, cx0, cx1);
    gld_lds16(bS[2] + ko, LB1 + dof[2]); gld_lds16(bS[3] + ko, LB1 + dof[3]);
    WAIT_VM(4);
    BARRIER(); LGKM0();
    __builtin_amdgcn_s_setprio(1); mm16(acc, 0, 2, af, bfH);
    __builtin_amdgcn_s_setprio(0);
    BARRIER();
    // ---------- e.q2 ----------
    rdA(af, LA0 + offA + 4096, cx0, cx1);
    gld_lds16(aS[0] + ko, LA1 + dof[0]); gld_lds16(aS[2] + ko, LA1 + dof[2]);
    BARRIER(); LGKM0();
    __builtin_amdgcn_s_setprio(1); mm16(acc, 4, 0, af, bfL);
    __builtin_amdgcn_s_setprio(0);
    BARRIER();
    // ---------- e.q3 ----------
    gld_lds16(aS[1] + ko, LA1 + dof[1]); gld_lds16(aS[3] + ko, LA1 + dof[3]);
    WAIT_VM(2);
    BARRIER(); __builtin_amdgcn_sched_barrier(0);
    __builtin_amdgcn_s_setprio(1); mm16(acc, 4, 2, af, bfH);
    __builtin_amdgcn_s_setprio(0);
    BARRIER();
    // ---------- o.q0 ----------
    rdA(af, LA1 + offA, cx0, cx1);
    rdB(bfL, LB1 + offB, cx0, cx1);
    if (hn) { gld_lds16(bS[0] + kn, LB0 + dof[0]); gld_lds16(bS[1] + kn, LB0 + dof[1]); }
    BARRIER(); LGKM0();
    __builtin_amdgcn_s_setprio(1); mm16(acc, 0, 0, af, bfL);
    __builtin_amdgcn_s_setprio(0);
    BARRIER();
    // ---------- o.q1 ----------
    rdB(bfH, LB1 + offB + 2048, cx0, cx1);
    if (hn) {
      gld_lds16(bS[2] + kn, LB0 + dof[2]); gld_lds16(bS[3] + kn, LB0 + dof[3]);
      WAIT_VM(4);
    } else {
      WAIT_VM(0);
    }
    BARRIER(); LGKM0();
    __builtin_amdgcn_s_setprio(1); mm16(acc, 0, 2, af, bfH);
    __builtin_amdgcn_s_setprio(0);
    BARRIER();
    // ---------- o.q2 ----------
    rdA(af, LA1 + offA + 4096, cx0, cx1);
    if (hn) { gld_lds16(aS[0] + kn, LA0 + dof[0]); gld_lds16(aS[2] + kn, LA0 + dof[2]); }
    BARRIER(); LGKM0();
    __builtin_amdgcn_s_setprio(1); mm16(acc, 4, 0, af, bfL);
    __builtin_amdgcn_s_setprio(0);
    BARRIER();
    // ---------- o.q3 ----------
    if (hn) { gld_lds16(aS[1] + kn, LA0 + dof[1]); gld_lds16(aS[3] + kn, LA0 + dof[3]); }
    WAIT_VM(2);
    BARRIER(); __builtin_amdgcn_sched_barrier(0);
    __builtin_amdgcn_s_setprio(1); mm16(acc, 4, 2, af, bfH);
    __builtin_amdgcn_s_setprio(0);
    BARRIER();
  }
}

// ---------------------------------------------------------------------------
// GEMM1: qkv = x_b @ W_attn^T, fused rope, LDS-coalesced epilogue.
// Grid: 768 blocks 1-D, XCD-swizzled: xcd=bid&7 gets 4 m-tiles x 8 n-tiles
// per round (A panels L2-resident per XCD). 3 rounds = Q, K, V.
// ---------------------------------------------------------------------------
__global__ __launch_bounds__(512, 2) void gemm_qkv(
    const u16* __restrict__ A, const u16* __restrict__ Bw,
    const float* __restrict__ freqs, int K,
    u16* __restrict__ Qp, u16* __restrict__ Kp, u16* __restrict__ Vp) {
  extern __shared__ u16 sm[];
  // XCD swizzle: bid -> (mt, nt); 768 = 8 xcd * 3 rounds * 32 (4m x 8n)
  const int bid = blockIdx.x;
  const int x = bid & 7, o = bid >> 3;
  const int rnd = o >> 5, w = o & 31;
  const int m0 = (x * 4 + (w & 3)) * 256;
  const int n0 = (rnd * 8 + (w >> 2)) * 256;

  f32x4 acc[8][4];
  gemm256_main(A, Bw, K, m0, n0, sm, acc);

  const int tid = threadIdx.x;
  const int lane = tid & 63, wv = tid >> 6;
  const int quad = lane >> 4, col = lane & 15;
  const int wm = wv >> 2, wn = wv & 3;

  const int which = n0 >> 11;          // 0=Q 1=K 2=V
  const int h0 = (n0 & 2047) >> 7;     // first head in tile
  const int b = m0 >> 11, t0 = m0 & 2047;
  const int hl = wn >> 1;              // head within tile (wave-uniform)

  __syncthreads();                     // LDS reuse: GEMM bufs -> epilogue tile

  if (which == 2) {
    // ---- V: stage tiled V^T [reg= hl*4+ktg][d 0..127][tc 0..63], XOR swz ----
#pragma unroll
    for (int j = 0; j < 4; ++j) {
      int d = (wn & 1) * 64 + j * 16 + col;     // 0..127
      int key = (d >> 1) & 7;
#pragma unroll
      for (int i = 0; i < 8; ++i)
#pragma unroll
        for (int r = 0; r < 4; ++r) {
          int tgl = wm * 128 + i * 16 + quad * 4 + r;   // 0..255
          int reg = hl * 4 + (tgl >> 6);
          int tc = tgl & 63;
          sm[reg * 8192 + d * 64 + (((tc >> 3) ^ key) << 3) + (tc & 7)] =
              f2b(acc[i][j][r]);
        }
    }
    __syncthreads();
    // coalesced store: 8 regions x 16KB, each contiguous in Vt
#pragma unroll
    for (int s = 0; s < 16; ++s) {
      int cch = tid + (s << 9);                  // 0..8191 chunks of 16B
      int reg = cch >> 10, ci = cch & 1023;
      int d = ci >> 3, cc = ci & 7;
      u16x8 v = *(const u16x8*)(sm + reg * 8192 + d * 64 +
                                (((cc ^ ((d >> 1) & 7))) << 3));
      int hh = reg >> 2, ktg = reg & 3;
      int kt = (t0 >> 6) + ktg;
      size_t off = (((size_t)((b * 16 + h0 + hh) * 32 + kt)) << 13) +
                   (size_t)d * 64 + (cc << 3);
      *(u16x8*)(Vp + off) = v;
    }
  } else {
    // ---- Q/K: rope + stage d'-interleaved rows [row= hl*256+t][d' 0..127] ----
    u16* dst = (which == 0) ? Qp : Kp;
    const bool evenlane = (col & 1) == 0;
    const int rlo = evenlane ? 0 : 2;
#pragma unroll
    for (int j = 0; j < 4; ++j) {
      int dd = (wn & 1) * 64 + j * 16 + col;    // 0..127 within head
      int jj = dd >> 1;                         // rope pair index 0..63
      float fr = freqs[jj];
#pragma unroll
      for (int i = 0; i < 8; ++i) {
        float oth[4];
#pragma unroll
        for (int r = 0; r < 4; ++r) oth[r] = __shfl_xor(acc[i][j][r], 1);
#pragma unroll
        for (int rr = 0; rr < 2; ++rr) {
          int r = rlo + rr;
          float q1 = evenlane ? acc[i][j][r] : oth[r];
          float q2 = evenlane ? oth[r] : acc[i][j][r];
          int tgl = wm * 128 + i * 16 + quad * 4 + r;
          int t = t0 + tgl;
          float theta = (float)t * fr;
          float rev = theta * 0.15915494309189535f;
          rev -= floorf(rev);
          float sn = __builtin_amdgcn_sinf(rev);
          float cs = __builtin_amdgcn_cosf(rev);
          // pack (q1*c - q2*s) at d'=2jj, (q1*s + q2*c) at d'=2jj+1
          unsigned pk = (unsigned)f2b(q1 * cs - q2 * sn) |
                        ((unsigned)f2b(q1 * sn + q2 * cs) << 16);
          int row = hl * 256 + tgl;             // 0..511
          int sc = (jj >> 2) ^ (row & 15);
          *(unsigned*)(sm + row * 128 + (sc << 3) + 2 * (jj & 3)) = pk;
        }
      }
    }
    __syncthreads();
    // coalesced store: 2 heads x 256 t-rows x 256B, contiguous per head
#pragma unroll
    for (int s = 0; s < 16; ++s) {
      int cch = tid + (s << 9);                  // 0..8191
      int row = cch >> 4, cc = cch & 15;
      u16x8 v = *(const u16x8*)(sm + row * 128 + ((cc ^ (row & 15)) << 3));
      int hh = row >> 8, tl = row & 255;
      size_t off = ((size_t)((b * 16 + h0 + hh) * 2048 + t0 + tl)) * 128 +
                   (cc << 3);
      *(u16x8*)(dst + off) = v;
    }
  }
}

// ---------------------------------------------------------------------------
// GEMM2: out = y @ W_proj^T, fp32 out. XCD-swizzled grid (isolates T1).
// ---------------------------------------------------------------------------
__global__ __launch_bounds__(512, 2) void gemm_proj(
    const u16* __restrict__ A, const u16* __restrict__ Bw,
    int N, int K, float* __restrict__ out) {
  extern __shared__ u16 sm[];
  const int bid = blockIdx.x;
  const int x = bid & 7, w = bid >> 3;          // 256 = 8 xcd * 32 (4m x 8n)
  const int m0 = (x * 4 + (w & 3)) * 256;
  const int n0 = (w >> 2) * 256;

  f32x4 acc[8][4];
  gemm256_main(A, Bw, K, m0, n0, sm, acc);

  const int tid = threadIdx.x;
  const int lane = tid & 63, wv = tid >> 6;
  const int quad = lane >> 4, col = lane & 15;
  const int wm = wv >> 2, wn = wv & 3;

#pragma unroll
  for (int i = 0; i < 8; ++i) {
    int mg = m0 + wm * 128 + i * 16 + quad * 4;
#pragma unroll
    for (int j = 0; j < 4; ++j) {
      int ng = n0 + wn * 64 + j * 16 + col;
#pragma unroll
      for (int r = 0; r < 4; ++r) out[(size_t)(mg + r) * N + ng] = acc[i][j][r];
    }
  }
}

// ---------------------------------------------------------------------------
// Flash attention, causal, paired q-tiles. 512 threads = 8 waves x 16 q rows.
// BC=64. K/V DOUBLE-BUFFERED with counted vmcnt (stage kt+1 while computing
// kt; each wave issues exactly 4 gld per tile -> WAIT_VM(4) + barrier).
// LDS 80KB dynamic -> 2 blocks/CU. Buffer select = arithmetic offset
// (no LDS-pointer arrays: hipcc addrspacecast static-init bug).
// ---------------------------------------------------------------------------
__global__ __launch_bounds__(512, 4) void fattn(
    const u16* __restrict__ Qb, const u16* __restrict__ Kb, const u16* __restrict__ Vt,
    u16* __restrict__ Yb) {
  extern __shared__ u16 smem[];
  // layout: K buf0 [0,8192), K buf1 [8192,16384), V buf0 [16384,24576),
  //         V buf1 [24576,32768), P [32768 + wv*1024, ...)
  u16* lP = smem + 32768 + (threadIdx.x >> 6) * 1024;  // per-wave [16][64]

  const int tid = threadIdx.x;
  const int lane = tid & 63, wv = tid >> 6;
  const int quad = lane >> 4, col = lane & 15;
  const int bh = blockIdx.x;
  const int p = blockIdx.y;
  const int b = bh >> 4, h = bh & 15;
  const size_t base = (size_t)bh << 18;
  const float kcomb = 0.08838834764831845f * 1.4426950408889634f;

#pragma unroll 1
  for (int phase = 0; phase < 2; ++phase) {
    const int tq = phase ? (15 - p) : p;
    const int qr0 = tq * 128 + wv * 16;
    const int dkt = qr0 >> 6;

    u16x8 qf[4];
#pragma unroll
    for (int t = 0; t < 4; ++t)
      qf[t] = *(const u16x8*)(Qb + base + (size_t)(qr0 + col) * 128 + t * 32 + quad * 8);

    f32x4 mrow = (f32x4){-1e30f, -1e30f, -1e30f, -1e30f};
    f32x4 lrow = (f32x4){0.f, 0.f, 0.f, 0.f};
    f32x4 o[8];
#pragma unroll
    for (int dt = 0; dt < 8; ++dt) o[dt] = (f32x4){0.f, 0.f, 0.f, 0.f};

    const int nkt = 2 * tq + 2;

    // ---- stage helper: wave wv<4 stages K rows, wv>=4 stages V^T.
    //      BI in {0,1} selects buffer by arithmetic offset. ----
#define FA_STAGE(KT, BI)                                                        \
    do {                                                                        \
      if (wv < 4) {                                                             \
        u16* lkd = smem + (BI) * 8192;                                          \
        _Pragma("unroll")                                                       \
        for (int u = 0; u < 4; ++u) {                                           \
          int row = wv * 16 + u * 4 + (lane >> 4);                              \
          int sc = (lane & 15) ^ (row & 15);                                    \
          gld_lds16(Kb + base + (size_t)((KT) * 64 + row) * 128 + (sc << 3),    \
                    lkd + (size_t)(wv * 16 + u * 4) * 128);                     \
        }                                                                       \
      } else {                                                                  \
        int vw = wv - 4;                                                        \
        u16* lvd = smem + 16384 + (BI) * 8192;                                  \
        const u16* vbase = Vt + ((size_t)(bh * 32 + (KT)) << 13);               \
        _Pragma("unroll")                                                       \
        for (int u = 0; u < 4; ++u) {                                           \
          int row = vw * 32 + u * 8 + (lane >> 3);                              \
          int sc = (lane & 7) ^ (row & 7);                                      \
          gld_lds16(vbase + (size_t)row * 64 + (sc << 3),                       \
                    lvd + (size_t)(vw * 32 + u * 8) * 64);                      \
        }                                                                       \
      }                                                                         \
    } while (0)

    FA_STAGE(0, 0);
    WAIT_VM(0);
    BARRIER();

#pragma unroll 1
    for (int kt = 0; kt < nkt; ++kt) {
      const int cur = kt & 1;
      if (kt + 1 < nkt) {
        FA_STAGE(kt + 1, cur ^ 1);
        WAIT_VM(4);          // kt's 4 loads (issued last iter) have landed
      } else {
        WAIT_VM(0);
      }
      BARRIER();             // all waves' kt loads landed

      if (kt <= dkt) {
        const u16* lK = smem + cur * 8192;
        const u16* lVt = smem + 16384 + cur * 8192;
        // QK^T
        f32x4 sv[4];
#pragma unroll
        for (int nt = 0; nt < 4; ++nt) {
          f32x4 s = (f32x4){0.f, 0.f, 0.f, 0.f};
#pragma unroll
          for (int t = 0; t < 4; ++t) {
            int krow = nt * 16 + col;
            u16x8 kf = *(const u16x8*)&lK[krow * 128 + ((((t << 2) | quad) ^ (krow & 15)) << 3)];
            s = MFMA16(qf[t], kf, s);
          }
          sv[nt] = s;
        }
#pragma unroll
        for (int nt = 0; nt < 4; ++nt)
#pragma unroll
          for (int r = 0; r < 4; ++r) sv[nt][r] *= kcomb;
        if (kt == dkt) {  // diagonal tile: causal mask
#pragma unroll
          for (int nt = 0; nt < 4; ++nt) {
            int cg = kt * 64 + nt * 16 + col;
#pragma unroll
            for (int r = 0; r < 4; ++r)
              if (cg > qr0 + quad * 4 + r) sv[nt][r] = -1e30f;
          }
        }
        f32x4 mx = sv[0];
#pragma unroll
        for (int nt = 1; nt < 4; ++nt)
#pragma unroll
          for (int r = 0; r < 4; ++r) mx[r] = fmaxf(mx[r], sv[nt][r]);
#pragma unroll
        for (int off = 1; off < 16; off <<= 1)
#pragma unroll
          for (int r = 0; r < 4; ++r) mx[r] = fmaxf(mx[r], __shfl_xor(mx[r], off));
        f32x4 alpha;
#pragma unroll
        for (int r = 0; r < 4; ++r) {
          float mn = fmaxf(mrow[r], mx[r]);
          alpha[r] = exp2f(mrow[r] - mn);
          mrow[r] = mn;
        }
        f32x4 ps = (f32x4){0.f, 0.f, 0.f, 0.f};
#pragma unroll
        for (int nt = 0; nt < 4; ++nt)
#pragma unroll
          for (int r = 0; r < 4; ++r) {
            float pe = exp2f(sv[nt][r] - mrow[r]);
            ps[r] += pe;
            int row = quad * 4 + r;
            int chn = ((nt << 1) | (col >> 3)) ^ (row & 7);
            lP[row * 64 + (chn << 3) + (col & 7)] = f2b(pe);
          }
#pragma unroll
        for (int off = 1; off < 16; off <<= 1)
#pragma unroll
          for (int r = 0; r < 4; ++r) ps[r] += __shfl_xor(ps[r], off);
#pragma unroll
        for (int r = 0; r < 4; ++r) lrow[r] = lrow[r] * alpha[r] + ps[r];
#pragma unroll
        for (int dt = 0; dt < 8; ++dt)
#pragma unroll
          for (int r = 0; r < 4; ++r) o[dt][r] *= alpha[r];
        // PV
#pragma unroll
        for (int t = 0; t < 2; ++t) {
          u16x8 pf = *(const u16x8*)&lP[col * 64 + ((((t << 2) | quad) ^ (col & 7)) << 3)];
#pragma unroll
          for (int dt = 0; dt < 8; ++dt) {
            int drow = dt * 16 + col;
            u16x8 vf = *(const u16x8*)&lVt[drow * 64 + ((((t << 2) | quad) ^ (drow & 7)) << 3)];
            o[dt] = MFMA16(pf, vf, o[dt]);
          }
        }
      }
      BARRIER();             // compute done before anyone stages over cur
    }  // kt

    // normalize + write Y (B*T, C) bf16
    f32x4 inv;
#pragma unroll
    for (int r = 0; r < 4; ++r) inv[r] = 1.0f / lrow[r];
#pragma unroll
    for (int dt = 0; dt < 8; ++dt)
#pragma unroll
      for (int r = 0; r < 4; ++r) {
        float y = o[dt][r] * inv[r];
        int q = qr0 + quad * 4 + r;
        Yb[((size_t)(b * 2048 + q)) * 2048 + h * 128 + dt * 16 + col] = f2b(y);
      }
  }  // phase
#undef FA_STAGE
}

// ---------------------------------------------------------------------------
extern "C" void kernel_launch(void* const* d_in, const int* in_sizes, int n_in,
                              void* d_out, int out_size, void* d_ws, size_t ws_size,
                              hipStream_t stream) {
  (void)in_sizes; (void)n_in; (void)out_size; (void)ws_size;
  const float* x     = (const float*)d_in[0];
  const float* freqs = (const float*)d_in[1];
  const float* Wattn = (const float*)d_in[2];
  const float* Wproj = (const float*)d_in[3];
  float* out = (float*)d_out;
  char* ws = (char*)d_ws;

  u16* Wq_b = (u16*)(ws + 0);
  u16* Wp_b = (u16*)(ws + 25165824);
  u16* x_b  = (u16*)(ws + 33554432);
  u16* Qb   = (u16*)(ws + 67108864);
  u16* Kb   = (u16*)(ws + 100663296);
  u16* Vt   = (u16*)(ws + 134217728);
  u16* Yb   = (u16*)(ws + 167772160);

  static bool attr_done = false;
  if (!attr_done) {
    (void)hipFuncSetAttribute((const void*)gemm_qkv,
                              hipFuncAttributeMaxDynamicSharedMemorySize, 131072);
    (void)hipFuncSetAttribute((const void*)gemm_proj,
                              hipFuncAttributeMaxDynamicSharedMemorySize, 131072);
    (void)hipFuncSetAttribute((const void*)fattn,
                              hipFuncAttributeMaxDynamicSharedMemorySize, 81920);
    attr_done = true;
  }

  cvt_bf16<<<6144, 256, 0, stream>>>((const float4*)Wattn, (u16x8*)Wq_b, 12582912 / 8);
  cvt_bf16<<<2048, 256, 0, stream>>>((const float4*)Wproj, (u16x8*)Wp_b, 4194304 / 8);
  cvt_bf16<<<8192, 256, 0, stream>>>((const float4*)x, (u16x8*)x_b, 16777216 / 8);

  gemm_qkv<<<dim3(768), 512, 131072, stream>>>(x_b, Wq_b, freqs, 2048, Qb, Kb, Vt);
  fattn<<<dim3(64, 8), 512, 81920, stream>>>(Qb, Kb, Vt, Yb);
  gemm_proj<<<dim3(256), 512, 131072, stream>>>(Yb, Wp_b, 2048, 2048, out);
}

// Round 4
// 585.815 us; speedup vs baseline: 1.0353x; 1.0353x over previous
//
#include <hip/hip_runtime.h>
#include <cstdint>
#include <cstddef>

// ---------------------------------------------------------------------------
// CausalSelfAttention, B=4 T=2048 C=2048 H=16 D=128, fp32 in/out.
// cvt(fp32->bf16) -> gemm_qkv (256x256 8-phase counted-vmcnt, fused rope,
// LDS-coalesced epilogue, XCD-swizzled grid; Q,K stored D-INTERLEAVED
// d' = 2*(d&63)+(d>>6) -- QK^T invariant under shared d-permutation;
// V^T tiled (B,H,32,128,64)) -> fattn (flash, K/V double-buffered counted
// vmcnt, hoisted stage addressing) -> gemm_proj (256x256 8-phase, natural 2D
// grid: XCD = n-tile -> B panel L2-resident per XCD, fp32 out).
// NOTE: no LDS-pointer arrays (hipcc addrspacecast static-init bug) --
// double-buffer selection is arithmetic offset off a single smem base.
// Workspace layout (bytes):
//   0         Wq_b   (6144x2048 bf16)  25165824
//   25165824  Wp_b   (2048x2048 bf16)   8388608
//   33554432  x_b    (8192x2048 bf16)  33554432
//   67108864  Qb     (B,H,T,D' bf16)   33554432   (d-interleaved)
//   100663296 Kb     (B,H,T,D' bf16)   33554432   (d-interleaved)
//   134217728 Vt     tiled (B,H,32,128,64) bf16  33554432
//   167772160 Yb     (8192x2048 bf16)  33554432
// ---------------------------------------------------------------------------

typedef unsigned short u16;
typedef u16    u16x8 __attribute__((ext_vector_type(8)));
typedef __bf16 bf16x8 __attribute__((ext_vector_type(8)));
typedef float  f32x4 __attribute__((ext_vector_type(4)));

#define MFMA16(a, b, c) __builtin_amdgcn_mfma_f32_16x16x32_bf16( \
    __builtin_bit_cast(bf16x8, (a)), __builtin_bit_cast(bf16x8, (b)), (c), 0, 0, 0)

static __device__ __forceinline__ u16 f2b(float f) {
  unsigned u = __builtin_bit_cast(unsigned, f);
  unsigned r = (u + 0x7FFFu + ((u >> 16) & 1u)) >> 16;   // RNE
  return (u16)r;
}

// async global->LDS, 16B per lane; lds dest = (wave-uniform base) + lane*16
static __device__ __forceinline__ void gld_lds16(const void* g, void* l) {
  __builtin_amdgcn_global_load_lds(
      (__attribute__((address_space(1))) unsigned int*)(void*)(g),
      (__attribute__((address_space(3))) unsigned int*)(l),
      16, 0, 0);
}

#define BARRIER() asm volatile("s_barrier" ::: "memory")
#define LGKM0()   do { asm volatile("s_waitcnt lgkmcnt(0)" ::: "memory"); \
                       __builtin_amdgcn_sched_barrier(0); } while (0)
#define WAIT_VM(n) asm volatile("s_waitcnt vmcnt(" #n ")" ::: "memory")

// ---------------------------------------------------------------------------
// fp32 -> bf16 conversion, 8 elements/thread
// ---------------------------------------------------------------------------
__global__ __launch_bounds__(256) void cvt_bf16(const float4* __restrict__ src,
                                                u16x8* __restrict__ dst, int n8) {
  int i = blockIdx.x * 256 + threadIdx.x;
  if (i >= n8) return;
  float4 a = src[i * 2], b = src[i * 2 + 1];
  u16x8 o;
  o[0] = f2b(a.x); o[1] = f2b(a.y); o[2] = f2b(a.z); o[3] = f2b(a.w);
  o[4] = f2b(b.x); o[5] = f2b(b.y); o[6] = f2b(b.z); o[7] = f2b(b.w);
  dst[i] = o;
}

// ---------------------------------------------------------------------------
// 256x256 8-phase GEMM main loop (shared by gemm_qkv / gemm_proj).
// A: MxK row-major bf16, Bw: NxK row-major bf16 (computes A @ Bw^T).
// acc[i][j]: rows wm*128+i*16, cols wn*64+j*16; C/D layout row=quad*4+reg,
// col=lane&15. LDS per buffer: A[256][64] then B[256][64], chunk swizzle.
// ---------------------------------------------------------------------------
static __device__ __forceinline__ void rdA(u16x8 (&af)[4][2], const u16* p,
                                           int cx0, int cx1) {
#pragma unroll
  for (int i = 0; i < 4; ++i) {
    af[i][0] = *(const u16x8*)(p + i * 1024 + cx0);
    af[i][1] = *(const u16x8*)(p + i * 1024 + cx1);
  }
}

static __device__ __forceinline__ void rdB(u16x8 (&bf)[2][2], const u16* p,
                                           int cx0, int cx1) {
#pragma unroll
  for (int j = 0; j < 2; ++j) {
    bf[j][0] = *(const u16x8*)(p + j * 1024 + cx0);
    bf[j][1] = *(const u16x8*)(p + j * 1024 + cx1);
  }
}

static __device__ __forceinline__ void mm16(f32x4 (&acc)[8][4], int ib, int jb,
                                            const u16x8 (&af)[4][2],
                                            const u16x8 (&bf)[2][2]) {
#pragma unroll
  for (int i = 0; i < 4; ++i)
#pragma unroll
    for (int j = 0; j < 2; ++j) {
      acc[ib + i][jb + j] = MFMA16(af[i][0], bf[j][0], acc[ib + i][jb + j]);
      acc[ib + i][jb + j] = MFMA16(af[i][1], bf[j][1], acc[ib + i][jb + j]);
    }
}

static __device__ __forceinline__ void gemm256_main(
    const u16* __restrict__ A, const u16* __restrict__ Bw, int K,
    int m0, int n0, u16* sm, f32x4 (&acc)[8][4]) {
  const int tid = threadIdx.x;
  const int lane = tid & 63, wv = tid >> 6;
  const int quad = lane >> 4, col = lane & 15;
  const int wm = wv >> 2, wn = wv & 3;

  u16* LA0 = sm;                // buf0 A  (32KB = 16384 u16)
  u16* LB0 = sm + 16384;        // buf0 B
  u16* LA1 = sm + 32768;        // buf1 A
  u16* LB1 = sm + 49152;        // buf1 B

#pragma unroll
  for (int i = 0; i < 8; ++i)
#pragma unroll
    for (int j = 0; j < 4; ++j) acc[i][j] = (f32x4){0.f, 0.f, 0.f, 0.f};

  const int r8 = lane >> 3, ch = lane & 7;
  const int sc8 = (ch ^ r8) << 3;           // row&7 == r8 for our row layout
  const u16 *aS[4], *bS[4];
  int dof[4];
#pragma unroll
  for (int u = 0; u < 4; ++u) {
    int row = u * 64 + wv * 8 + r8;
    aS[u] = A + (size_t)(m0 + row) * K + sc8;
    bS[u] = Bw + (size_t)(n0 + row) * K + sc8;
    dof[u] = (u * 64 + wv * 8) * 64;
  }

  const int cx0 = ((quad) ^ (col & 7)) << 3;
  const int cx1 = ((4 | quad) ^ (col & 7)) << 3;
  const int offA = (wm * 128 + col) * 64;
  const int offB = (wn * 64 + col) * 64;

  // ---- prologue: stage tile0 -> buf0, order B0..B3, A0, A2, A1, A3 ----
  gld_lds16(bS[0], LB0 + dof[0]); gld_lds16(bS[1], LB0 + dof[1]);
  gld_lds16(bS[2], LB0 + dof[2]); gld_lds16(bS[3], LB0 + dof[3]);
  gld_lds16(aS[0], LA0 + dof[0]); gld_lds16(aS[2], LA0 + dof[2]);
  gld_lds16(aS[1], LA0 + dof[1]); gld_lds16(aS[3], LA0 + dof[3]);
  WAIT_VM(2);          // first 6 (B0-3, A0, A2) landed; A1,A3 in flight
  BARRIER();

  u16x8 af[4][2], bfL[2][2], bfH[2][2];
  const int nIt = K >> 7;
#pragma unroll 1
  for (int it = 0; it < nIt; ++it) {
    const size_t ko = (size_t)it * 128 + 64;
    const size_t kn = (size_t)it * 128 + 128;
    const bool hn = (it + 1 < nIt);

    // ---------- e.q0 ----------
    rdA(af, LA0 + offA, cx0, cx1);
    rdB(bfL, LB0 + offB, cx0, cx1);
    gld_lds16(bS[0] + ko, LB1 + dof[0]); gld_lds16(bS[1] + ko, LB1 + dof[1]);
    BARRIER(); LGKM0();
    __builtin_amdgcn_s_setprio(1); mm16(acc, 0, 0, af, bfL);
    __builtin_amdgcn_s_setprio(0);
    BARRIER();
    // ---------- e.q1 ----------
    rdB(bfH, LB0 + offB + 2048, cx0, cx1);
    gld_lds16(bS[2] + ko, LB1 + dof[2]); gld_lds16(bS[3] + ko, LB1 + dof[3]);
    WAIT_VM(4);
    BARRIER(); LGKM0();
    __builtin_amdgcn_s_setprio(1); mm16(acc, 0, 2, af, bfH);
    __builtin_amdgcn_s_setprio(0);
    BARRIER();
    // ---------- e.q2 ----------
    rdA(af, LA0 + offA + 4096, cx0, cx1);
    gld_lds16(aS[0] + ko, LA1 + dof[0]); gld_lds16(aS[2] + ko, LA1 + dof[2]);
    BARRIER(); LGKM0();
    __builtin_amdgcn_s_setprio(1); mm16(acc, 4, 0, af, bfL);
    __builtin_amdgcn_s_setprio(0);
    BARRIER();
    // ---------- e.q3 ----------
    gld_lds16(aS[1] + ko, LA1 + dof[1]); gld_lds16(aS[3] + ko, LA1 + dof[3]);
    WAIT_VM(2);
    BARRIER(); __builtin_amdgcn_sched_barrier(0);
    __builtin_amdgcn_s_setprio(1); mm16(acc, 4, 2, af, bfH);
    __builtin_amdgcn_s_setprio(0);
    BARRIER();
    // ---------- o.q0 ----------
    rdA(af, LA1 + offA, cx0, cx1);
    rdB(bfL, LB1 + offB, cx0, cx1);
    if (hn) { gld_lds16(bS[0] + kn, LB0 + dof[0]); gld_lds16(bS[1] + kn, LB0 + dof[1]); }
    BARRIER(); LGKM0();
    __builtin_amdgcn_s_setprio(1); mm16(acc, 0, 0, af, bfL);
    __builtin_amdgcn_s_setprio(0);
    BARRIER();
    // ---------- o.q1 ----------
    rdB(bfH, LB1 + offB + 2048, cx0, cx1);
    if (hn) {
      gld_lds16(bS[2] + kn, LB0 + dof[2]); gld_lds16(bS[3] + kn, LB0 + dof[3]);
      WAIT_VM(4);
    } else {
      WAIT_VM(0);
    }
    BARRIER(); LGKM0();
    __builtin_amdgcn_s_setprio(1); mm16(acc, 0, 2, af, bfH);
    __builtin_amdgcn_s_setprio(0);
    BARRIER();
    // ---------- o.q2 ----------
    rdA(af, LA1 + offA + 4096, cx0, cx1);
    if (hn) { gld_lds16(aS[0] + kn, LA0 + dof[0]); gld_lds16(aS[2] + kn, LA0 + dof[2]); }
    BARRIER(); LGKM0();
    __builtin_amdgcn_s_setprio(1); mm16(acc, 4, 0, af, bfL);
    __builtin_amdgcn_s_setprio(0);
    BARRIER();
    // ---------- o.q3 ----------
    if (hn) { gld_lds16(aS[1] + kn, LA0 + dof[1]); gld_lds16(aS[3] + kn, LA0 + dof[3]); }
    WAIT_VM(2);
    BARRIER(); __builtin_amdgcn_sched_barrier(0);
    __builtin_amdgcn_s_setprio(1); mm16(acc, 4, 2, af, bfH);
    __builtin_amdgcn_s_setprio(0);
    BARRIER();
  }
}

// ---------------------------------------------------------------------------
// GEMM1: qkv = x_b @ W_attn^T, fused rope, LDS-coalesced epilogue.
// Grid: 768 blocks 1-D, XCD-swizzled: xcd=bid&7 gets 4 m-tiles x 8 n-tiles
// per round (A panels L2-resident per XCD). 3 rounds = Q, K, V.
// ---------------------------------------------------------------------------
__global__ __launch_bounds__(512, 2) void gemm_qkv(
    const u16* __restrict__ A, const u16* __restrict__ Bw,
    const float* __restrict__ freqs, int K,
    u16* __restrict__ Qp, u16* __restrict__ Kp, u16* __restrict__ Vp) {
  extern __shared__ u16 sm[];
  // XCD swizzle: bid -> (mt, nt); 768 = 8 xcd * 3 rounds * 32 (4m x 8n)
  const int bid = blockIdx.x;
  const int x = bid & 7, o = bid >> 3;
  const int rnd = o >> 5, w = o & 31;
  const int m0 = (x * 4 + (w & 3)) * 256;
  const int n0 = (rnd * 8 + (w >> 2)) * 256;

  f32x4 acc[8][4];
  gemm256_main(A, Bw, K, m0, n0, sm, acc);

  const int tid = threadIdx.x;
  const int lane = tid & 63, wv = tid >> 6;
  const int quad = lane >> 4, col = lane & 15;
  const int wm = wv >> 2, wn = wv & 3;

  const int which = n0 >> 11;          // 0=Q 1=K 2=V
  const int h0 = (n0 & 2047) >> 7;     // first head in tile
  const int b = m0 >> 11, t0 = m0 & 2047;
  const int hl = wn >> 1;              // head within tile (wave-uniform)

  // NOTE: no barrier needed here -- gemm256_main ends in BARRIER() with all
  // lgkm/vm drained (last phase has no outstanding gld; ds_reads consumed).

  if (which == 2) {
    // ---- V: stage tiled V^T [reg= hl*4+ktg][d 0..127][tc 0..63], XOR swz.
    //      b32-packed writes: r-pairs are address-adjacent and 4B-aligned. ----
#pragma unroll
    for (int j = 0; j < 4; ++j) {
      int d = (wn & 1) * 64 + j * 16 + col;     // 0..127
      int key = (d >> 1) & 7;
#pragma unroll
      for (int i = 0; i < 8; ++i) {
        int tbase = wm * 128 + i * 16 + quad * 4;     // tgl for r=0 (mult of 4)
        int reg = hl * 4 + (tbase >> 6);
        int tc0 = tbase & 63;
        u16* d0 = sm + reg * 8192 + d * 64 + ((((tc0 >> 3) ^ key)) << 3) + (tc0 & 7);
        *(unsigned*)d0 = (unsigned)f2b(acc[i][j][0]) |
                         ((unsigned)f2b(acc[i][j][1]) << 16);
        *(unsigned*)(d0 + 2) = (unsigned)f2b(acc[i][j][2]) |
                               ((unsigned)f2b(acc[i][j][3]) << 16);
      }
    }
    __syncthreads();
    // coalesced store: 8 regions x 16KB, each contiguous in Vt
#pragma unroll
    for (int s = 0; s < 16; ++s) {
      int cch = tid + (s << 9);                  // 0..8191 chunks of 16B
      int reg = cch >> 10, ci = cch & 1023;
      int d = ci >> 3, cc = ci & 7;
      u16x8 v = *(const u16x8*)(sm + reg * 8192 + d * 64 +
                                (((cc ^ ((d >> 1) & 7))) << 3));
      int hh = reg >> 2, ktg = reg & 3;
      int kt = (t0 >> 6) + ktg;
      size_t off = (((size_t)((b * 16 + h0 + hh) * 32 + kt)) << 13) +
                   (size_t)d * 64 + (cc << 3);
      *(u16x8*)(Vp + off) = v;
    }
  } else {
    // ---- Q/K: rope + stage d'-interleaved rows [row= hl*256+t][d' 0..127] ----
    u16* dst = (which == 0) ? Qp : Kp;
    const bool evenlane = (col & 1) == 0;
    const int rlo = evenlane ? 0 : 2;
#pragma unroll
    for (int j = 0; j < 4; ++j) {
      int dd = (wn & 1) * 64 + j * 16 + col;    // 0..127 within head
      int jj = dd >> 1;                         // rope pair index 0..63
      float fr = freqs[jj];
#pragma unroll
      for (int i = 0; i < 8; ++i) {
        float oth[4];
#pragma unroll
        for (int r = 0; r < 4; ++r) oth[r] = __shfl_xor(acc[i][j][r], 1);
#pragma unroll
        for (int rr = 0; rr < 2; ++rr) {
          int r = rlo + rr;
          float q1 = evenlane ? acc[i][j][r] : oth[r];
          float q2 = evenlane ? oth[r] : acc[i][j][r];
          int tgl = wm * 128 + i * 16 + quad * 4 + r;
          int t = t0 + tgl;
          float theta = (float)t * fr;
          float rev = theta * 0.15915494309189535f;
          rev -= floorf(rev);
          float sn = __builtin_amdgcn_sinf(rev);
          float cs = __builtin_amdgcn_cosf(rev);
          // pack (q1*c - q2*s) at d'=2jj, (q1*s + q2*c) at d'=2jj+1
          unsigned pk = (unsigned)f2b(q1 * cs - q2 * sn) |
                        ((unsigned)f2b(q1 * sn + q2 * cs) << 16);
          int row = hl * 256 + tgl;             // 0..511
          int sc = (jj >> 2) ^ (row & 15);
          *(unsigned*)(sm + row * 128 + (sc << 3) + 2 * (jj & 3)) = pk;
        }
      }
    }
    __syncthreads();
    // coalesced store: 2 heads x 256 t-rows x 256B, contiguous per head
#pragma unroll
    for (int s = 0; s < 16; ++s) {
      int cch = tid + (s << 9);                  // 0..8191
      int row = cch >> 4, cc = cch & 15;
      u16x8 v = *(const u16x8*)(sm + row * 128 + ((cc ^ (row & 15)) << 3));
      int hh = row >> 8, tl = row & 255;
      size_t off = ((size_t)((b * 16 + h0 + hh) * 2048 + t0 + tl)) * 128 +
                   (cc << 3);
      *(u16x8*)(dst + off) = v;
    }
  }
}

// ---------------------------------------------------------------------------
// GEMM2: out = y @ W_proj^T, fp32 out. Natural 2D grid dim3(8,32):
// linearized x-fast => XCD = blockIdx.x = n-tile; each XCD's 32 concurrent
// blocks share ONE 1MiB B panel (L2-resident) and stream A. (Explicit 4m x 8n
// swizzle regressed: streamed 8MiB of B through 4MiB L2.)
// ---------------------------------------------------------------------------
__global__ __launch_bounds__(512, 2) void gemm_proj(
    const u16* __restrict__ A, const u16* __restrict__ Bw,
    int N, int K, float* __restrict__ out) {
  extern __shared__ u16 sm[];
  const int m0 = blockIdx.y * 256, n0 = blockIdx.x * 256;

  f32x4 acc[8][4];
  gemm256_main(A, Bw, K, m0, n0, sm, acc);

  const int tid = threadIdx.x;
  const int lane = tid & 63, wv = tid >> 6;
  const int quad = lane >> 4, col = lane & 15;
  const int wm = wv >> 2, wn = wv & 3;

#pragma unroll
  for (int i = 0; i < 8; ++i) {
    int mg = m0 + wm * 128 + i * 16 + quad * 4;
#pragma unroll
    for (int j = 0; j < 4; ++j) {
      int ng = n0 + wn * 64 + j * 16 + col;
#pragma unroll
      for (int r = 0; r < 4; ++r) out[(size_t)(mg + r) * N + ng] = acc[i][j][r];
    }
  }
}

// ---------------------------------------------------------------------------
// Flash attention, causal, paired q-tiles. 512 threads = 8 waves x 16 q rows.
// BC=64. K/V DOUBLE-BUFFERED with counted vmcnt (stage kt+1 while computing
// kt; each wave issues exactly 4 gld per tile -> WAIT_VM(4) + barrier).
// Stage addressing hoisted: K-tile and V-tile strides are both 8192 u16, so
// staging = srcBase + kt*8192 + so[u] with per-lane offsets computed once.
// LDS 80KB dynamic -> 2 blocks/CU.
// ---------------------------------------------------------------------------
__global__ __launch_bounds__(512, 4) void fattn(
    const u16* __restrict__ Qb, const u16* __restrict__ Kb, const u16* __restrict__ Vt,
    u16* __restrict__ Yb) {
  extern __shared__ u16 smem[];
  // layout: K buf0 [0,8192), K buf1 [8192,16384), V buf0 [16384,24576),
  //         V buf1 [24576,32768), P [32768 + wv*1024, ...)
  u16* lP = smem + 32768 + (threadIdx.x >> 6) * 1024;  // per-wave [16][64]

  const int tid = threadIdx.x;
  const int lane = tid & 63, wv = tid >> 6;
  const int quad = lane >> 4, col = lane & 15;
  const int bh = blockIdx.x;
  const int p = blockIdx.y;
  const int b = bh >> 4, h = bh & 15;
  const size_t base = (size_t)bh << 18;        // 2048*128 == 32*8192 == 1<<18
  const float kcomb = 0.08838834764831845f * 1.4426950408889634f;

  // ---- hoisted staging geometry (kt-independent) ----
  const u16* srcBase;                 // + kt*8192 per tile
  u16* ldsBase;                       // + BI*8192 per buffer
  int so[4], lo[4];
  if (wv < 4) {
    srcBase = Kb + base;
    ldsBase = smem;
#pragma unroll
    for (int u = 0; u < 4; ++u) {
      int row = wv * 16 + u * 4 + (lane >> 4);
      int sc = (lane & 15) ^ (row & 15);
      so[u] = row * 128 + (sc << 3);
      lo[u] = (wv * 16 + u * 4) * 128;
    }
  } else {
    int vw = wv - 4;
    srcBase = Vt + base;
    ldsBase = smem + 16384;
#pragma unroll
    for (int u = 0; u < 4; ++u) {
      int row = vw * 32 + u * 8 + (lane >> 3);
      int sc = (lane & 7) ^ (row & 7);
      so[u] = row * 64 + (sc << 3);
      lo[u] = (vw * 32 + u * 8) * 64;
    }
  }

#define FA_STAGE(KT, BI)                                                        \
    do {                                                                        \
      const u16* s_ = srcBase + (size_t)(KT) * 8192;                            \
      u16* d_ = ldsBase + (BI) * 8192;                                          \
      gld_lds16(s_ + so[0], d_ + lo[0]); gld_lds16(s_ + so[1], d_ + lo[1]);     \
      gld_lds16(s_ + so[2], d_ + lo[2]); gld_lds16(s_ + so[3], d_ + lo[3]);     \
    } while (0)

#pragma unroll 1
  for (int phase = 0; phase < 2; ++phase) {
    const int tq = phase ? (15 - p) : p;
    const int qr0 = tq * 128 + wv * 16;
    const int dkt = qr0 >> 6;

    u16x8 qf[4];
#pragma unroll
    for (int t = 0; t < 4; ++t)
      qf[t] = *(const u16x8*)(Qb + base + (size_t)(qr0 + col) * 128 + t * 32 + quad * 8);

    f32x4 mrow = (f32x4){-1e30f, -1e30f, -1e30f, -1e30f};
    f32x4 lrow = (f32x4){0.f, 0.f, 0.f, 0.f};
    f32x4 o[8];
#pragma unroll
    for (int dt = 0; dt < 8; ++dt) o[dt] = (f32x4){0.f, 0.f, 0.f, 0.f};

    const int nkt = 2 * tq + 2;

    FA_STAGE(0, 0);
    WAIT_VM(0);
    BARRIER();

#pragma unroll 1
    for (int kt = 0; kt < nkt; ++kt) {
      const int cur = kt & 1;
      if (kt + 1 < nkt) {
        FA_STAGE(kt + 1, cur ^ 1);
        WAIT_VM(4);          // kt's 4 loads (issued last iter) have landed
      } else {
        WAIT_VM(0);
      }
      BARRIER();             // all waves' kt loads landed

      if (kt <= dkt) {
        const u16* lK = smem + cur * 8192;
        const u16* lVt = smem + 16384 + cur * 8192;
        // QK^T
        f32x4 sv[4];
#pragma unroll
        for (int nt = 0; nt < 4; ++nt) {
          f32x4 s = (f32x4){0.f, 0.f, 0.f, 0.f};
#pragma unroll
          for (int t = 0; t < 4; ++t) {
            int krow = nt * 16 + col;
            u16x8 kf = *(const u16x8*)&lK[krow * 128 + ((((t << 2) | quad) ^ (krow & 15)) << 3)];
            s = MFMA16(qf[t], kf, s);
          }
          sv[nt] = s;
        }
#pragma unroll
        for (int nt = 0; nt < 4; ++nt)
#pragma unroll
          for (int r = 0; r < 4; ++r) sv[nt][r] *= kcomb;
        if (kt == dkt) {  // diagonal tile: causal mask
#pragma unroll
          for (int nt = 0; nt < 4; ++nt) {
            int cg = kt * 64 + nt * 16 + col;
#pragma unroll
            for (int r = 0; r < 4; ++r)
              if (cg > qr0 + quad * 4 + r) sv[nt][r] = -1e30f;
          }
        }
        f32x4 mx = sv[0];
#pragma unroll
        for (int nt = 1; nt < 4; ++nt)
#pragma unroll
          for (int r = 0; r < 4; ++r) mx[r] = fmaxf(mx[r], sv[nt][r]);
#pragma unroll
        for (int off = 1; off < 16; off <<= 1)
#pragma unroll
          for (int r = 0; r < 4; ++r) mx[r] = fmaxf(mx[r], __shfl_xor(mx[r], off));
        f32x4 alpha;
#pragma unroll
        for (int r = 0; r < 4; ++r) {
          float mn = fmaxf(mrow[r], mx[r]);
          alpha[r] = exp2f(mrow[r] - mn);
          mrow[r] = mn;
        }
        f32x4 ps = (f32x4){0.f, 0.f, 0.f, 0.f};
#pragma unroll
        for (int nt = 0; nt < 4; ++nt)
#pragma unroll
          for (int r = 0; r < 4; ++r) {
            float pe = exp2f(sv[nt][r] - mrow[r]);
            ps[r] += pe;
            int row = quad * 4 + r;
            int chn = ((nt << 1) | (col >> 3)) ^ (row & 7);
            lP[row * 64 + (chn << 3) + (col & 7)] = f2b(pe);
          }
#pragma unroll
        for (int off = 1; off < 16; off <<= 1)
#pragma unroll
          for (int r = 0; r < 4; ++r) ps[r] += __shfl_xor(ps[r], off);
#pragma unroll
        for (int r = 0; r < 4; ++r) lrow[r] = lrow[r] * alpha[r] + ps[r];
#pragma unroll
        for (int dt = 0; dt < 8; ++dt)
#pragma unroll
          for (int r = 0; r < 4; ++r) o[dt][r] *= alpha[r];
        // PV
#pragma unroll
        for (int t = 0; t < 2; ++t) {
          u16x8 pf = *(const u16x8*)&lP[col * 64 + ((((t << 2) | quad) ^ (col & 7)) << 3)];
#pragma unroll
          for (int dt = 0; dt < 8; ++dt) {
            int drow = dt * 16 + col;
            u16x8 vf = *(const u16x8*)&lVt[drow * 64 + ((((t << 2) | quad) ^ (drow & 7)) << 3)];
            o[dt] = MFMA16(pf, vf, o[dt]);
          }
        }
      }
      BARRIER();             // compute done before anyone stages over cur
    }  // kt

    // normalize + write Y (B*T, C) bf16
    f32x4 inv;
#pragma unroll
    for (int r = 0; r < 4; ++r) inv[r] = 1.0f / lrow[r];
#pragma unroll
    for (int dt = 0; dt < 8; ++dt)
#pragma unroll
      for (int r = 0; r < 4; ++r) {
        float y = o[dt][r] * inv[r];
        int q = qr0 + quad * 4 + r;
        Yb[((size_t)(b * 2048 + q)) * 2048 + h * 128 + dt * 16 + col] = f2b(y);
      }
  }  // phase
#undef FA_STAGE
}

// ---------------------------------------------------------------------------
extern "C" void kernel_launch(void* const* d_in, const int* in_sizes, int n_in,
                              void* d_out, int out_size, void* d_ws, size_t ws_size,
                              hipStream_t stream) {
  (void)in_sizes; (void)n_in; (void)out_size; (void)ws_size;
  const float* x     = (const float*)d_in[0];
  const float* freqs = (const float*)d_in[1];
  const float* Wattn = (const float*)d_in[2];
  const float* Wproj = (const float*)d_in[3];
  float* out = (float*)d_out;
  char* ws = (char*)d_ws;

  u16* Wq_b = (u16*)(ws + 0);
  u16* Wp_b = (u16*)(ws + 25165824);
  u16* x_b  = (u16*)(ws + 33554432);
  u16* Qb   = (u16*)(ws + 67108864);
  u16* Kb   = (u16*)(ws + 100663296);
  u16* Vt   = (u16*)(ws + 134217728);
  u16* Yb   = (u16*)(ws + 167772160);

  static bool attr_done = false;
  if (!attr_done) {
    (void)hipFuncSetAttribute((const void*)gemm_qkv,
                              hipFuncAttributeMaxDynamicSharedMemorySize, 131072);
    (void)hipFuncSetAttribute((const void*)gemm_proj,
                              hipFuncAttributeMaxDynamicSharedMemorySize, 131072);
    (void)hipFuncSetAttribute((const void*)fattn,
                              hipFuncAttributeMaxDynamicSharedMemorySize, 81920);
    attr_done = true;
  }

  cvt_bf16<<<6144, 256, 0, stream>>>((const float4*)Wattn, (u16x8*)Wq_b, 12582912 / 8);
  cvt_bf16<<<2048, 256, 0, stream>>>((const float4*)Wproj, (u16x8*)Wp_b, 4194304 / 8);
  cvt_bf16<<<8192, 256, 0, stream>>>((const float4*)x, (u16x8*)x_b, 16777216 / 8);

  gemm_qkv<<<dim3(768), 512, 131072, stream>>>(x_b, Wq_b, freqs, 2048, Qb, Kb, Vt);
  fattn<<<dim3(64, 8), 512, 81920, stream>>>(Qb, Kb, Vt, Yb);
  gemm_proj<<<dim3(8, 32), 512, 131072, stream>>>(Yb, Wp_b, 2048, 2048, out);
}

// Round 5
// 583.202 us; speedup vs baseline: 1.0400x; 1.0045x over previous
//
#include <hip/hip_runtime.h>
#include <cstdint>
#include <cstddef>

// ---------------------------------------------------------------------------
// CausalSelfAttention, B=4 T=2048 C=2048 H=16 D=128, fp32 in/out.
// cvt(fp32->bf16) -> gemm_qkv (256x256 8-phase counted-vmcnt, fused rope,
// LDS-coalesced epilogue, XCD-swizzled grid; Q,K stored D-INTERLEAVED
// d' = 2*(d&63)+(d>>6) -- QK^T invariant under shared d-permutation;
// V^T tiled (B,H,32,128,64)) -> fattn (flash, SINGLE-buffer 48KB static LDS
// => 3 blocks/CU; hoisted stage addressing, setprio on MFMA, defer-max)
// -> gemm_proj (256x256 8-phase, natural 2D grid, fp32 out).
// HISTORY: 80KB dbuf fattn (r3/r4) cut residency 3->2 blocks/CU and lost
// ~35us -- this kernel is latency-bound (8.7% HBM, ~12% MFMA) and lives on
// TLP. Do not grow its LDS.
// Workspace layout (bytes):
//   0         Wq_b   (6144x2048 bf16)  25165824
//   25165824  Wp_b   (2048x2048 bf16)   8388608
//   33554432  x_b    (8192x2048 bf16)  33554432
//   67108864  Qb     (B,H,T,D' bf16)   33554432   (d-interleaved)
//   100663296 Kb     (B,H,T,D' bf16)   33554432   (d-interleaved)
//   134217728 Vt     tiled (B,H,32,128,64) bf16  33554432
//   167772160 Yb     (8192x2048 bf16)  33554432
// ---------------------------------------------------------------------------

typedef unsigned short u16;
typedef u16    u16x8 __attribute__((ext_vector_type(8)));
typedef __bf16 bf16x8 __attribute__((ext_vector_type(8)));
typedef float  f32x4 __attribute__((ext_vector_type(4)));

#define MFMA16(a, b, c) __builtin_amdgcn_mfma_f32_16x16x32_bf16( \
    __builtin_bit_cast(bf16x8, (a)), __builtin_bit_cast(bf16x8, (b)), (c), 0, 0, 0)

static __device__ __forceinline__ u16 f2b(float f) {
  unsigned u = __builtin_bit_cast(unsigned, f);
  unsigned r = (u + 0x7FFFu + ((u >> 16) & 1u)) >> 16;   // RNE
  return (u16)r;
}

// async global->LDS, 16B per lane; lds dest = (wave-uniform base) + lane*16
static __device__ __forceinline__ void gld_lds16(const void* g, void* l) {
  __builtin_amdgcn_global_load_lds(
      (__attribute__((address_space(1))) unsigned int*)(void*)(g),
      (__attribute__((address_space(3))) unsigned int*)(l),
      16, 0, 0);
}

#define BARRIER() asm volatile("s_barrier" ::: "memory")
#define LGKM0()   do { asm volatile("s_waitcnt lgkmcnt(0)" ::: "memory"); \
                       __builtin_amdgcn_sched_barrier(0); } while (0)
#define WAIT_VM(n) asm volatile("s_waitcnt vmcnt(" #n ")" ::: "memory")

// ---------------------------------------------------------------------------
// fp32 -> bf16 conversion, 8 elements/thread
// ---------------------------------------------------------------------------
__global__ __launch_bounds__(256) void cvt_bf16(const float4* __restrict__ src,
                                                u16x8* __restrict__ dst, int n8) {
  int i = blockIdx.x * 256 + threadIdx.x;
  if (i >= n8) return;
  float4 a = src[i * 2], b = src[i * 2 + 1];
  u16x8 o;
  o[0] = f2b(a.x); o[1] = f2b(a.y); o[2] = f2b(a.z); o[3] = f2b(a.w);
  o[4] = f2b(b.x); o[5] = f2b(b.y); o[6] = f2b(b.z); o[7] = f2b(b.w);
  dst[i] = o;
}

// ---------------------------------------------------------------------------
// 256x256 8-phase GEMM main loop (shared by gemm_qkv / gemm_proj).
// A: MxK row-major bf16, Bw: NxK row-major bf16 (computes A @ Bw^T).
// acc[i][j]: rows wm*128+i*16, cols wn*64+j*16; C/D layout row=quad*4+reg,
// col=lane&15. LDS per buffer: A[256][64] then B[256][64], chunk swizzle.
// ---------------------------------------------------------------------------
static __device__ __forceinline__ void rdA(u16x8 (&af)[4][2], const u16* p,
                                           int cx0, int cx1) {
#pragma unroll
  for (int i = 0; i < 4; ++i) {
    af[i][0] = *(const u16x8*)(p + i * 1024 + cx0);
    af[i][1] = *(const u16x8*)(p + i * 1024 + cx1);
  }
}

static __device__ __forceinline__ void rdB(u16x8 (&bf)[2][2], const u16* p,
                                           int cx0, int cx1) {
#pragma unroll
  for (int j = 0; j < 2; ++j) {
    bf[j][0] = *(const u16x8*)(p + j * 1024 + cx0);
    bf[j][1] = *(const u16x8*)(p + j * 1024 + cx1);
  }
}

static __device__ __forceinline__ void mm16(f32x4 (&acc)[8][4], int ib, int jb,
                                            const u16x8 (&af)[4][2],
                                            const u16x8 (&bf)[2][2]) {
#pragma unroll
  for (int i = 0; i < 4; ++i)
#pragma unroll
    for (int j = 0; j < 2; ++j) {
      acc[ib + i][jb + j] = MFMA16(af[i][0], bf[j][0], acc[ib + i][jb + j]);
      acc[ib + i][jb + j] = MFMA16(af[i][1], bf[j][1], acc[ib + i][jb + j]);
    }
}

static __device__ __forceinline__ void gemm256_main(
    const u16* __restrict__ A, const u16* __restrict__ Bw, int K,
    int m0, int n0, u16* sm, f32x4 (&acc)[8][4]) {
  const int tid = threadIdx.x;
  const int lane = tid & 63, wv = tid >> 6;
  const int quad = lane >> 4, col = lane & 15;
  const int wm = wv >> 2, wn = wv & 3;

  u16* LA0 = sm;                // buf0 A  (32KB = 16384 u16)
  u16* LB0 = sm + 16384;        // buf0 B
  u16* LA1 = sm + 32768;        // buf1 A
  u16* LB1 = sm + 49152;        // buf1 B

#pragma unroll
  for (int i = 0; i < 8; ++i)
#pragma unroll
    for (int j = 0; j < 4; ++j) acc[i][j] = (f32x4){0.f, 0.f, 0.f, 0.f};

  const int r8 = lane >> 3, ch = lane & 7;
  const int sc8 = (ch ^ r8) << 3;           // row&7 == r8 for our row layout
  const u16 *aS[4], *bS[4];
  int dof[4];
#pragma unroll
  for (int u = 0; u < 4; ++u) {
    int row = u * 64 + wv * 8 + r8;
    aS[u] = A + (size_t)(m0 + row) * K + sc8;
    bS[u] = Bw + (size_t)(n0 + row) * K + sc8;
    dof[u] = (u * 64 + wv * 8) * 64;
  }

  const int cx0 = ((quad) ^ (col & 7)) << 3;
  const int cx1 = ((4 | quad) ^ (col & 7)) << 3;
  const int offA = (wm * 128 + col) * 64;
  const int offB = (wn * 64 + col) * 64;

  // ---- prologue: stage tile0 -> buf0, order B0..B3, A0, A2, A1, A3 ----
  gld_lds16(bS[0], LB0 + dof[0]); gld_lds16(bS[1], LB0 + dof[1]);
  gld_lds16(bS[2], LB0 + dof[2]); gld_lds16(bS[3], LB0 + dof[3]);
  gld_lds16(aS[0], LA0 + dof[0]); gld_lds16(aS[2], LA0 + dof[2]);
  gld_lds16(aS[1], LA0 + dof[1]); gld_lds16(aS[3], LA0 + dof[3]);
  WAIT_VM(2);          // first 6 (B0-3, A0, A2) landed; A1,A3 in flight
  BARRIER();

  u16x8 af[4][2], bfL[2][2], bfH[2][2];
  const int nIt = K >> 7;
#pragma unroll 1
  for (int it = 0; it < nIt; ++it) {
    const size_t ko = (size_t)it * 128 + 64;
    const size_t kn = (size_t)it * 128 + 128;
    const bool hn = (it + 1 < nIt);

    // ---------- e.q0 ----------
    rdA(af, LA0 + offA, cx0, cx1);
    rdB(bfL, LB0 + offB, cx0, cx1);
    gld_lds16(bS[0] + ko, LB1 + dof[0]); gld_lds16(bS[1] + ko, LB1 + dof[1]);
    BARRIER(); LGKM0();
    __builtin_amdgcn_s_setprio(1); mm16(acc, 0, 0, af, bfL);
    __builtin_amdgcn_s_setprio(0);
    BARRIER();
    // ---------- e.q1 ----------
    rdB(bfH, LB0 + offB + 2048, cx0, cx1);
    gld_lds16(bS[2] + ko, LB1 + dof[2]); gld_lds16(bS[3] + ko, LB1 + dof[3]);
    WAIT_VM(4);
    BARRIER(); LGKM0();
    __builtin_amdgcn_s_setprio(1); mm16(acc, 0, 2, af, bfH);
    __builtin_amdgcn_s_setprio(0);
    BARRIER();
    // ---------- e.q2 ----------
    rdA(af, LA0 + offA + 4096, cx0, cx1);
    gld_lds16(aS[0] + ko, LA1 + dof[0]); gld_lds16(aS[2] + ko, LA1 + dof[2]);
    BARRIER(); LGKM0();
    __builtin_amdgcn_s_setprio(1); mm16(acc, 4, 0, af, bfL);
    __builtin_amdgcn_s_setprio(0);
    BARRIER();
    // ---------- e.q3 ----------
    gld_lds16(aS[1] + ko, LA1 + dof[1]); gld_lds16(aS[3] + ko, LA1 + dof[3]);
    WAIT_VM(2);
    BARRIER(); __builtin_amdgcn_sched_barrier(0);
    __builtin_amdgcn_s_setprio(1); mm16(acc, 4, 2, af, bfH);
    __builtin_amdgcn_s_setprio(0);
    BARRIER();
    // ---------- o.q0 ----------
    rdA(af, LA1 + offA, cx0, cx1);
    rdB(bfL, LB1 + offB, cx0, cx1);
    if (hn) { gld_lds16(bS[0] + kn, LB0 + dof[0]); gld_lds16(bS[1] + kn, LB0 + dof[1]); }
    BARRIER(); LGKM0();
    __builtin_amdgcn_s_setprio(1); mm16(acc, 0, 0, af, bfL);
    __builtin_amdgcn_s_setprio(0);
    BARRIER();
    // ---------- o.q1 ----------
    rdB(bfH, LB1 + offB + 2048, cx0, cx1);
    if (hn) {
      gld_lds16(bS[2] + kn, LB0 + dof[2]); gld_lds16(bS[3] + kn, LB0 + dof[3]);
      WAIT_VM(4);
    } else {
      WAIT_VM(0);
    }
    BARRIER(); LGKM0();
    __builtin_amdgcn_s_setprio(1); mm16(acc, 0, 2, af, bfH);
    __builtin_amdgcn_s_setprio(0);
    BARRIER();
    // ---------- o.q2 ----------
    rdA(af, LA1 + offA + 4096, cx0, cx1);
    if (hn) { gld_lds16(aS[0] + kn, LA0 + dof[0]); gld_lds16(aS[2] + kn, LA0 + dof[2]); }
    BARRIER(); LGKM0();
    __builtin_amdgcn_s_setprio(1); mm16(acc, 4, 0, af, bfL);
    __builtin_amdgcn_s_setprio(0);
    BARRIER();
    // ---------- o.q3 ----------
    if (hn) { gld_lds16(aS[1] + kn, LA0 + dof[1]); gld_lds16(aS[3] + kn, LA0 + dof[3]); }
    WAIT_VM(2);
    BARRIER(); __builtin_amdgcn_sched_barrier(0);
    __builtin_amdgcn_s_setprio(1); mm16(acc, 4, 2, af, bfH);
    __builtin_amdgcn_s_setprio(0);
    BARRIER();
  }
}

// ---------------------------------------------------------------------------
// GEMM1: qkv = x_b @ W_attn^T, fused rope, LDS-coalesced epilogue.
// Grid: 768 blocks 1-D, XCD-swizzled: xcd=bid&7 gets 4 m-tiles x 8 n-tiles
// per round (A panels L2-resident per XCD). 3 rounds = Q, K, V.
// ---------------------------------------------------------------------------
__global__ __launch_bounds__(512, 2) void gemm_qkv(
    const u16* __restrict__ A, const u16* __restrict__ Bw,
    const float* __restrict__ freqs, int K,
    u16* __restrict__ Qp, u16* __restrict__ Kp, u16* __restrict__ Vp) {
  extern __shared__ u16 sm[];
  // XCD swizzle: bid -> (mt, nt); 768 = 8 xcd * 3 rounds * 32 (4m x 8n)
  const int bid = blockIdx.x;
  const int x = bid & 7, o = bid >> 3;
  const int rnd = o >> 5, w = o & 31;
  const int m0 = (x * 4 + (w & 3)) * 256;
  const int n0 = (rnd * 8 + (w >> 2)) * 256;

  f32x4 acc[8][4];
  gemm256_main(A, Bw, K, m0, n0, sm, acc);

  const int tid = threadIdx.x;
  const int lane = tid & 63, wv = tid >> 6;
  const int quad = lane >> 4, col = lane & 15;
  const int wm = wv >> 2, wn = wv & 3;

  const int which = n0 >> 11;          // 0=Q 1=K 2=V
  const int h0 = (n0 & 2047) >> 7;     // first head in tile
  const int b = m0 >> 11, t0 = m0 & 2047;
  const int hl = wn >> 1;              // head within tile (wave-uniform)

  // NOTE: no barrier needed here -- gemm256_main ends in BARRIER() with all
  // lgkm/vm drained (last phase has no outstanding gld; ds_reads consumed).

  if (which == 2) {
    // ---- V: stage tiled V^T [reg= hl*4+ktg][d 0..127][tc 0..63], XOR swz.
    //      b32-packed writes: r-pairs are address-adjacent and 4B-aligned. ----
#pragma unroll
    for (int j = 0; j < 4; ++j) {
      int d = (wn & 1) * 64 + j * 16 + col;     // 0..127
      int key = (d >> 1) & 7;
#pragma unroll
      for (int i = 0; i < 8; ++i) {
        int tbase = wm * 128 + i * 16 + quad * 4;     // tgl for r=0 (mult of 4)
        int reg = hl * 4 + (tbase >> 6);
        int tc0 = tbase & 63;
        u16* d0 = sm + reg * 8192 + d * 64 + ((((tc0 >> 3) ^ key)) << 3) + (tc0 & 7);
        *(unsigned*)d0 = (unsigned)f2b(acc[i][j][0]) |
                         ((unsigned)f2b(acc[i][j][1]) << 16);
        *(unsigned*)(d0 + 2) = (unsigned)f2b(acc[i][j][2]) |
                               ((unsigned)f2b(acc[i][j][3]) << 16);
      }
    }
    __syncthreads();
    // coalesced store: 8 regions x 16KB, each contiguous in Vt
#pragma unroll
    for (int s = 0; s < 16; ++s) {
      int cch = tid + (s << 9);                  // 0..8191 chunks of 16B
      int reg = cch >> 10, ci = cch & 1023;
      int d = ci >> 3, cc = ci & 7;
      u16x8 v = *(const u16x8*)(sm + reg * 8192 + d * 64 +
                                (((cc ^ ((d >> 1) & 7))) << 3));
      int hh = reg >> 2, ktg = reg & 3;
      int kt = (t0 >> 6) + ktg;
      size_t off = (((size_t)((b * 16 + h0 + hh) * 32 + kt)) << 13) +
                   (size_t)d * 64 + (cc << 3);
      *(u16x8*)(Vp + off) = v;
    }
  } else {
    // ---- Q/K: rope + stage d'-interleaved rows [row= hl*256+t][d' 0..127] ----
    u16* dst = (which == 0) ? Qp : Kp;
    const bool evenlane = (col & 1) == 0;
    const int rlo = evenlane ? 0 : 2;
#pragma unroll
    for (int j = 0; j < 4; ++j) {
      int dd = (wn & 1) * 64 + j * 16 + col;    // 0..127 within head
      int jj = dd >> 1;                         // rope pair index 0..63
      float fr = freqs[jj];
#pragma unroll
      for (int i = 0; i < 8; ++i) {
        float oth[4];
#pragma unroll
        for (int r = 0; r < 4; ++r) oth[r] = __shfl_xor(acc[i][j][r], 1);
#pragma unroll
        for (int rr = 0; rr < 2; ++rr) {
          int r = rlo + rr;
          float q1 = evenlane ? acc[i][j][r] : oth[r];
          float q2 = evenlane ? oth[r] : acc[i][j][r];
          int tgl = wm * 128 + i * 16 + quad * 4 + r;
          int t = t0 + tgl;
          float theta = (float)t * fr;
          float rev = theta * 0.15915494309189535f;
          rev -= floorf(rev);
          float sn = __builtin_amdgcn_sinf(rev);
          float cs = __builtin_amdgcn_cosf(rev);
          // pack (q1*c - q2*s) at d'=2jj, (q1*s + q2*c) at d'=2jj+1
          unsigned pk = (unsigned)f2b(q1 * cs - q2 * sn) |
                        ((unsigned)f2b(q1 * sn + q2 * cs) << 16);
          int row = hl * 256 + tgl;             // 0..511
          int sc = (jj >> 2) ^ (row & 15);
          *(unsigned*)(sm + row * 128 + (sc << 3) + 2 * (jj & 3)) = pk;
        }
      }
    }
    __syncthreads();
    // coalesced store: 2 heads x 256 t-rows x 256B, contiguous per head
#pragma unroll
    for (int s = 0; s < 16; ++s) {
      int cch = tid + (s << 9);                  // 0..8191
      int row = cch >> 4, cc = cch & 15;
      u16x8 v = *(const u16x8*)(sm + row * 128 + ((cc ^ (row & 15)) << 3));
      int hh = row >> 8, tl = row & 255;
      size_t off = ((size_t)((b * 16 + h0 + hh) * 2048 + t0 + tl)) * 128 +
                   (cc << 3);
      *(u16x8*)(dst + off) = v;
    }
  }
}

// ---------------------------------------------------------------------------
// GEMM2: out = y @ W_proj^T, fp32 out. Natural 2D grid dim3(8,32):
// linearized x-fast => XCD = blockIdx.x = n-tile; each XCD's 32 concurrent
// blocks share ONE 1MiB B panel (L2-resident) and stream A.
// ---------------------------------------------------------------------------
__global__ __launch_bounds__(512, 2) void gemm_proj(
    const u16* __restrict__ A, const u16* __restrict__ Bw,
    int N, int K, float* __restrict__ out) {
  extern __shared__ u16 sm[];
  const int m0 = blockIdx.y * 256, n0 = blockIdx.x * 256;

  f32x4 acc[8][4];
  gemm256_main(A, Bw, K, m0, n0, sm, acc);

  const int tid = threadIdx.x;
  const int lane = tid & 63, wv = tid >> 6;
  const int quad = lane >> 4, col = lane & 15;
  const int wm = wv >> 2, wn = wv & 3;

#pragma unroll
  for (int i = 0; i < 8; ++i) {
    int mg = m0 + wm * 128 + i * 16 + quad * 4;
#pragma unroll
    for (int j = 0; j < 4; ++j) {
      int ng = n0 + wn * 64 + j * 16 + col;
#pragma unroll
      for (int r = 0; r < 4; ++r) out[(size_t)(mg + r) * N + ng] = acc[i][j][r];
    }
  }
}

// ---------------------------------------------------------------------------
// Flash attention, causal, paired q-tiles (uniform 36 kv-iters per block).
// 512 threads = 8 waves x 16 q rows. BC=64. SINGLE-buffer 48KB static LDS
// -> 3 blocks/CU (24 waves) -- TLP is this kernel's latency hiding; the 80KB
// dbuf variant (2 blocks/CU) was ~35us slower. Waves 0-3 stage K, 4-7 stage
// tiled V^T, hoisted addressing. setprio(1) around MFMA clusters (T5).
// Defer-max (T13): skip o-rescale when __all(mx-mrow <= 8) in log2 units.
// ---------------------------------------------------------------------------
__global__ __launch_bounds__(512, 4) void fattn(
    const u16* __restrict__ Qb, const u16* __restrict__ Kb, const u16* __restrict__ Vt,
    u16* __restrict__ Yb) {
  __shared__ alignas(16) u16 lK[64 * 128];    // [kc][d], chunk16 xor row&15
  __shared__ alignas(16) u16 lV[128 * 64];    // [d][kc], chunk8 xor row&7
  __shared__ alignas(16) u16 lPs[8][16 * 64]; // per-wave [qr][kc], chunk8 xor

  const int tid = threadIdx.x;
  const int lane = tid & 63, wv = tid >> 6;
  const int quad = lane >> 4, col = lane & 15;
  const int bh = blockIdx.x;                   // fast dim -> same-bh same XCD
  const int p = blockIdx.y;
  const int b = bh >> 4, h = bh & 15;
  const size_t base = (size_t)bh << 18;        // 2048*128 == 32*8192
  const float kcomb = 0.08838834764831845f * 1.4426950408889634f;
  u16* lP = lPs[wv];

  // ---- hoisted staging geometry (kt-independent); both tiles 8192 u16 ----
  const u16* srcBase;
  u16* dA0; u16* dA1; u16* dA2; u16* dA3;
  int so[4];
  if (wv < 4) {
    srcBase = Kb + base;
#pragma unroll
    for (int u = 0; u < 4; ++u) {
      int row = wv * 16 + u * 4 + (lane >> 4);
      int sc = (lane & 15) ^ (row & 15);
      so[u] = row * 128 + (sc << 3);
    }
    dA0 = lK + (wv * 16 + 0) * 128; dA1 = lK + (wv * 16 + 4) * 128;
    dA2 = lK + (wv * 16 + 8) * 128; dA3 = lK + (wv * 16 + 12) * 128;
  } else {
    int vw = wv - 4;
    srcBase = Vt + base;
#pragma unroll
    for (int u = 0; u < 4; ++u) {
      int row = vw * 32 + u * 8 + (lane >> 3);
      int sc = (lane & 7) ^ (row & 7);
      so[u] = row * 64 + (sc << 3);
    }
    dA0 = lV + (vw * 32 + 0) * 64;  dA1 = lV + (vw * 32 + 8) * 64;
    dA2 = lV + (vw * 32 + 16) * 64; dA3 = lV + (vw * 32 + 24) * 64;
  }

#define FA_STAGE(KT)                                                            \
    do {                                                                        \
      const u16* s_ = srcBase + (size_t)(KT) * 8192;                            \
      gld_lds16(s_ + so[0], dA0); gld_lds16(s_ + so[1], dA1);                   \
      gld_lds16(s_ + so[2], dA2); gld_lds16(s_ + so[3], dA3);                   \
    } while (0)

#pragma unroll 1
  for (int phase = 0; phase < 2; ++phase) {
    const int tq = phase ? (15 - p) : p;       // q-tile index (128 rows)
    const int qr0 = tq * 128 + wv * 16;        // wave's 16 q rows
    const int dkt = qr0 >> 6;                  // wave's diagonal kv-tile

    u16x8 qf[4];
#pragma unroll
    for (int t = 0; t < 4; ++t)
      qf[t] = *(const u16x8*)(Qb + base + (size_t)(qr0 + col) * 128 + t * 32 + quad * 8);

    f32x4 mrow = (f32x4){-1e30f, -1e30f, -1e30f, -1e30f};
    f32x4 lrow = (f32x4){0.f, 0.f, 0.f, 0.f};
    f32x4 o[8];
#pragma unroll
    for (int dt = 0; dt < 8; ++dt) o[dt] = (f32x4){0.f, 0.f, 0.f, 0.f};

    const int nkt = 2 * tq + 2;
#pragma unroll 1
    for (int kt = 0; kt < nkt; ++kt) {
      __syncthreads();          // all waves done reading previous tile
      FA_STAGE(kt);
      __syncthreads();          // staging drained (vm drain in syncthreads)

      if (kt <= dkt) {
        // QK^T
        f32x4 sv[4];
        __builtin_amdgcn_s_setprio(1);
#pragma unroll
        for (int nt = 0; nt < 4; ++nt) {
          f32x4 s = (f32x4){0.f, 0.f, 0.f, 0.f};
#pragma unroll
          for (int t = 0; t < 4; ++t) {
            int krow = nt * 16 + col;
            u16x8 kf = *(const u16x8*)&lK[krow * 128 + ((((t << 2) | quad) ^ (krow & 15)) << 3)];
            s = MFMA16(qf[t], kf, s);
          }
          sv[nt] = s;
        }
        __builtin_amdgcn_s_setprio(0);
#pragma unroll
        for (int nt = 0; nt < 4; ++nt)
#pragma unroll
          for (int r = 0; r < 4; ++r) sv[nt][r] *= kcomb;
        if (kt == dkt) {  // diagonal tile: causal mask
#pragma unroll
          for (int nt = 0; nt < 4; ++nt) {
            int cg = kt * 64 + nt * 16 + col;
#pragma unroll
            for (int r = 0; r < 4; ++r)
              if (cg > qr0 + quad * 4 + r) sv[nt][r] = -1e30f;
          }
        }
        // row max over nt and the 16 lanes holding this row
        f32x4 mx = sv[0];
#pragma unroll
        for (int nt = 1; nt < 4; ++nt)
#pragma unroll
          for (int r = 0; r < 4; ++r) mx[r] = fmaxf(mx[r], sv[nt][r]);
#pragma unroll
        for (int off = 1; off < 16; off <<= 1)
#pragma unroll
          for (int r = 0; r < 4; ++r) mx[r] = fmaxf(mx[r], __shfl_xor(mx[r], off));
        // defer-max (T13): only rescale when some row grew by > 8 (log2)
        bool cheap = (mx[0] - mrow[0] <= 8.f) & (mx[1] - mrow[1] <= 8.f) &
                     (mx[2] - mrow[2] <= 8.f) & (mx[3] - mrow[3] <= 8.f);
        if (!__all(cheap)) {
          f32x4 alpha;
#pragma unroll
          for (int r = 0; r < 4; ++r) {
            float mn = fmaxf(mrow[r], mx[r]);
            alpha[r] = exp2f(mrow[r] - mn);
            mrow[r] = mn;
            lrow[r] *= alpha[r];
          }
#pragma unroll
          for (int dt = 0; dt < 8; ++dt)
#pragma unroll
            for (int r = 0; r < 4; ++r) o[dt][r] *= alpha[r];
        }
        f32x4 ps = (f32x4){0.f, 0.f, 0.f, 0.f};
#pragma unroll
        for (int nt = 0; nt < 4; ++nt)
#pragma unroll
          for (int r = 0; r < 4; ++r) {
            float pe = exp2f(sv[nt][r] - mrow[r]);
            ps[r] += pe;
            int row = quad * 4 + r;
            int chn = ((nt << 1) | (col >> 3)) ^ (row & 7);
            lP[row * 64 + (chn << 3) + (col & 7)] = f2b(pe);
          }
#pragma unroll
        for (int off = 1; off < 16; off <<= 1)
#pragma unroll
          for (int r = 0; r < 4; ++r) ps[r] += __shfl_xor(ps[r], off);
#pragma unroll
        for (int r = 0; r < 4; ++r) lrow[r] += ps[r];
        // PV: o += P(16x64) x V^T(64x128 as B-operand from lV)
        __builtin_amdgcn_s_setprio(1);
#pragma unroll
        for (int t = 0; t < 2; ++t) {
          u16x8 pf = *(const u16x8*)&lP[col * 64 + ((((t << 2) | quad) ^ (col & 7)) << 3)];
#pragma unroll
          for (int dt = 0; dt < 8; ++dt) {
            int drow = dt * 16 + col;
            u16x8 vf = *(const u16x8*)&lV[drow * 64 + ((((t << 2) | quad) ^ (drow & 7)) << 3)];
            o[dt] = MFMA16(pf, vf, o[dt]);
          }
        }
        __builtin_amdgcn_s_setprio(0);
      }
    }  // kt

    // normalize + write Y (B*T, C) bf16
    f32x4 inv;
#pragma unroll
    for (int r = 0; r < 4; ++r) inv[r] = 1.0f / lrow[r];
#pragma unroll
    for (int dt = 0; dt < 8; ++dt)
#pragma unroll
      for (int r = 0; r < 4; ++r) {
        float y = o[dt][r] * inv[r];
        int q = qr0 + quad * 4 + r;
        Yb[((size_t)(b * 2048 + q)) * 2048 + h * 128 + dt * 16 + col] = f2b(y);
      }
  }  // phase
#undef FA_STAGE
}

// ---------------------------------------------------------------------------
extern "C" void kernel_launch(void* const* d_in, const int* in_sizes, int n_in,
                              void* d_out, int out_size, void* d_ws, size_t ws_size,
                              hipStream_t stream) {
  (void)in_sizes; (void)n_in; (void)out_size; (void)ws_size;
  const float* x     = (const float*)d_in[0];
  const float* freqs = (const float*)d_in[1];
  const float* Wattn = (const float*)d_in[2];
  const float* Wproj = (const float*)d_in[3];
  float* out = (float*)d_out;
  char* ws = (char*)d_ws;

  u16* Wq_b = (u16*)(ws + 0);
  u16* Wp_b = (u16*)(ws + 25165824);
  u16* x_b  = (u16*)(ws + 33554432);
  u16* Qb   = (u16*)(ws + 67108864);
  u16* Kb   = (u16*)(ws + 100663296);
  u16* Vt   = (u16*)(ws + 134217728);
  u16* Yb   = (u16*)(ws + 167772160);

  static bool attr_done = false;
  if (!attr_done) {
    (void)hipFuncSetAttribute((const void*)gemm_qkv,
                              hipFuncAttributeMaxDynamicSharedMemorySize, 131072);
    (void)hipFuncSetAttribute((const void*)gemm_proj,
                              hipFuncAttributeMaxDynamicSharedMemorySize, 131072);
    attr_done = true;
  }

  cvt_bf16<<<6144, 256, 0, stream>>>((const float4*)Wattn, (u16x8*)Wq_b, 12582912 / 8);
  cvt_bf16<<<2048, 256, 0, stream>>>((const float4*)Wproj, (u16x8*)Wp_b, 4194304 / 8);
  cvt_bf16<<<8192, 256, 0, stream>>>((const float4*)x, (u16x8*)x_b, 16777216 / 8);

  gemm_qkv<<<dim3(768), 512, 131072, stream>>>(x_b, Wq_b, freqs, 2048, Qb, Kb, Vt);
  fattn<<<dim3(64, 8), 512, 0, stream>>>(Qb, Kb, Vt, Yb);
  gemm_proj<<<dim3(8, 32), 512, 131072, stream>>>(Yb, Wp_b, 2048, 2048, out);
}